// Round 1
// baseline (423.946 us; speedup 1.0000x reference)
//
#include <hip/hip_runtime.h>

// ---------- types / helpers ----------
typedef __attribute__((ext_vector_type(8))) short short8;   // 8 bf16 = 4 VGPRs
typedef __attribute__((ext_vector_type(4))) float f32x4;

__device__ __forceinline__ float bf2f(unsigned short u) {
    union { unsigned int i; float f; } x; x.i = ((unsigned int)u) << 16; return x.f;
}
__device__ __forceinline__ unsigned short f2bf(float f) {
    union { float f; unsigned int i; } x; x.f = f;
    unsigned int r = x.i + 0x7fffu + ((x.i >> 16) & 1u);   // RTNE
    return (unsigned short)(r >> 16);
}
__device__ __forceinline__ void async_copy16(const void* g, void* l) {
    __builtin_amdgcn_global_load_lds(
        (const __attribute__((address_space(1))) void*)g,
        (__attribute__((address_space(3))) void*)l,
        16, 0, 0);
}

// ---------- fp32 -> bf16 convert (x) ----------
__global__ __launch_bounds__(256) void conv_f32_bf16(const float* __restrict__ in,
                                                     unsigned short* __restrict__ out, int n) {
    int i = (blockIdx.x * 256 + threadIdx.x) * 4;
    if (i < n) {
        float4 v = *(const float4*)&in[i];
        ushort4 o;
        o.x = f2bf(v.x); o.y = f2bf(v.y); o.z = f2bf(v.z); o.w = f2bf(v.w);
        *(ushort4*)&out[i] = o;
    }
}

// ---------- transpose + convert: in (R x C fp32) -> out (C x R bf16) ----------
__global__ __launch_bounds__(256) void transpose_to_bf16(const float* __restrict__ in,
                                                         unsigned short* __restrict__ out,
                                                         int R, int C) {
    __shared__ float tile[32][33];                 // +1 pad: no bank conflicts
    int bx = blockIdx.x * 32;                      // C index
    int by = blockIdx.y * 32;                      // R index
    int tx = threadIdx.x & 31, ty = threadIdx.x >> 5;   // 32 x 8
    #pragma unroll
    for (int r = ty; r < 32; r += 8)
        tile[r][tx] = in[(size_t)(by + r) * C + bx + tx];
    __syncthreads();
    #pragma unroll
    for (int r = ty; r < 32; r += 8)
        out[(size_t)(bx + r) * R + by + tx] = f2bf(tile[tx][r]);
}

// ---------- m97-style bf16 GEMM: C[M,N] = A[M,K] * Bt[N,K]^T + bias ----------
// BM=BN=128, BK=32, 256 threads (4 waves, 2x2), each wave 64x64 via 4x4 MFMA 16x16x32.
template<bool OUT_BF16>
__global__ __launch_bounds__(256) void gemm_bf16(const unsigned short* __restrict__ A, int lda,
                                                 const unsigned short* __restrict__ Bt, int ldb,
                                                 const float* __restrict__ bias,
                                                 void* __restrict__ C, int ldc, int K) {
    __shared__ short As[128 * 32];   // 8 KB, row-major [128][32]
    __shared__ short Bs[128 * 32];   // 8 KB, row-major [128][32] (rows = output cols)

    const int tid    = threadIdx.x;
    const int lane   = tid & 63;
    const int wid    = tid >> 6;
    const int wave_m = wid >> 1, wave_n = wid & 1;
    const int quad   = lane >> 4;
    const int l16    = lane & 15;
    const int m0     = blockIdx.x * 128;
    const int n0     = blockIdx.y * 128;

    // staging: thread -> 16B chunk; row = tid/4, col8 = (tid%4)*8 (lane-order == LDS order)
    const int srow = tid >> 2;
    const int scol = (tid & 3) * 8;

    f32x4 acc[4][4] = {};

    for (int k0 = 0; k0 < K; k0 += 32) {
        __syncthreads();   // previous iter's LDS reads done
        async_copy16(A  + (size_t)(m0 + srow)      * lda + k0 + scol, &As[tid * 8]);
        async_copy16(A  + (size_t)(m0 + srow + 64) * lda + k0 + scol, &As[2048 + tid * 8]);
        async_copy16(Bt + (size_t)(n0 + srow)      * ldb + k0 + scol, &Bs[tid * 8]);
        async_copy16(Bt + (size_t)(n0 + srow + 64) * ldb + k0 + scol, &Bs[2048 + tid * 8]);
        __syncthreads();   // implies vmcnt(0) drain of global_load_lds

        short8 af[4], bfr[4];
        #pragma unroll
        for (int i = 0; i < 4; i++)
            af[i] = *(const short8*)&As[(wave_m * 64 + i * 16 + l16) * 32 + quad * 8];
        #pragma unroll
        for (int j = 0; j < 4; j++)
            bfr[j] = *(const short8*)&Bs[(wave_n * 64 + j * 16 + l16) * 32 + quad * 8];
        #pragma unroll
        for (int i = 0; i < 4; i++)
            #pragma unroll
            for (int j = 0; j < 4; j++)
                acc[i][j] = __builtin_amdgcn_mfma_f32_16x16x32_bf16(af[i], bfr[j], acc[i][j], 0, 0, 0);
    }

    // epilogue: C/D layout col = lane&15, row = quad*4 + r   [measured m89/m91]
    #pragma unroll
    for (int j = 0; j < 4; j++) {
        const int gcol = n0 + wave_n * 64 + j * 16 + l16;
        const float bv = bias[gcol];
        #pragma unroll
        for (int i = 0; i < 4; i++) {
            const int grow = m0 + wave_m * 64 + i * 16 + quad * 4;
            #pragma unroll
            for (int r = 0; r < 4; r++) {
                float v = acc[i][j][r] + bv;
                if (OUT_BF16)
                    ((unsigned short*)C)[(size_t)(grow + r) * ldc + gcol] = f2bf(v);
                else
                    ((float*)C)[(size_t)(grow + r) * ldc + gcol] = v;
            }
        }
    }
}

// ---------- block reduction ----------
__device__ __forceinline__ float block_sum(float v, float* sbuf, int tid) {
    #pragma unroll
    for (int o = 32; o; o >>= 1) v += __shfl_down(v, o, 64);
    __syncthreads();                       // protect sbuf reuse
    if ((tid & 63) == 0) sbuf[tid >> 6] = v;
    __syncthreads();
    return sbuf[0] + sbuf[1] + sbuf[2] + sbuf[3];
}

// ---------- per-row q/k norms + kv pool ----------
// qkv: [16384][3072] bf16 (q | k | v). 16 rows per block; kv partials in registers.
#define NK_ROWS 16
__global__ __launch_bounds__(256) void norm_kv(const unsigned short* __restrict__ qkv,
                                               float* __restrict__ rnq,
                                               float* __restrict__ kv, int T) {
    __shared__ float sbuf[4];
    const int tid  = threadIdx.x;
    const int row0 = blockIdx.x * NK_ROWS;
    const int b    = row0 / T;            // T % NK_ROWS == 0 -> uniform per block
    const int d    = tid * 4;
    float a0 = 0.f, a1 = 0.f, a2 = 0.f, a3 = 0.f;

    for (int rr = 0; rr < NK_ROWS; ++rr) {
        const size_t base = (size_t)(row0 + rr) * 3072;
        ushort4 qu = *(const ushort4*)&qkv[base + d];
        float q0 = bf2f(qu.x), q1 = bf2f(qu.y), q2 = bf2f(qu.z), q3 = bf2f(qu.w);
        float sq = block_sum(q0*q0 + q1*q1 + q2*q2 + q3*q3, sbuf, tid);
        if (tid == 0) rnq[row0 + rr] = rsqrtf(sq);

        ushort4 ku = *(const ushort4*)&qkv[base + 1024 + d];
        float k0 = bf2f(ku.x), k1 = bf2f(ku.y), k2 = bf2f(ku.z), k3 = bf2f(ku.w);
        float rk = rsqrtf(block_sum(k0*k0 + k1*k1 + k2*k2 + k3*k3, sbuf, tid));

        ushort4 vu = *(const ushort4*)&qkv[base + 2048 + d];
        a0 += k0 * rk * bf2f(vu.x);
        a1 += k1 * rk * bf2f(vu.y);
        a2 += k2 * rk * bf2f(vu.z);
        a3 += k3 * rk * bf2f(vu.w);
    }
    atomicAdd(&kv[b * 1024 + d + 0], a0);
    atomicAdd(&kv[b * 1024 + d + 1], a1);
    atomicAdd(&kv[b * 1024 + d + 2], a2);
    atomicAdd(&kv[b * 1024 + d + 3], a3);
}

// ---------- out = q_hat * kv  (written into qkv's dead v-region, bf16) ----------
__global__ __launch_bounds__(256) void scale_q(unsigned short* __restrict__ qkv,
                                               const float* __restrict__ rnq,
                                               const float* __restrict__ kv, int T) {
    const int t = blockIdx.x;
    const int b = t / T;
    const int d = threadIdx.x * 4;
    const float rq = rnq[t];
    const size_t base = (size_t)t * 3072;
    ushort4 qu = *(const ushort4*)&qkv[base + d];
    float4 kvv = *(const float4*)&kv[b * 1024 + d];
    ushort4 o;
    o.x = f2bf(bf2f(qu.x) * rq * kvv.x);
    o.y = f2bf(bf2f(qu.y) * rq * kvv.y);
    o.z = f2bf(bf2f(qu.z) * rq * kvv.z);
    o.w = f2bf(bf2f(qu.w) * rq * kvv.w);
    *(ushort4*)&qkv[base + 2048 + d] = o;
}

extern "C" void kernel_launch(void* const* d_in, const int* in_sizes, int n_in,
                              void* d_out, int out_size, void* d_ws, size_t ws_size,
                              hipStream_t stream) {
    const float* x    = (const float*)d_in[0];   // (4,4096,1024)
    const float* Wqkv = (const float*)d_in[1];   // (1024,3072)
    const float* bqkv = (const float*)d_in[2];   // (3072)
    const float* Wout = (const float*)d_in[3];   // (1024,1024)
    const float* bout = (const float*)d_in[4];   // (1024)
    float* out = (float*)d_out;                  // (4,4096,1024) fp32

    // workspace layout (~136 MB)
    char* ws = (char*)d_ws;
    unsigned short* x_bf  = (unsigned short*)(ws + 0);           // 16384*1024*2 = 32 MB
    unsigned short* WqkvT = (unsigned short*)(ws + 33554432);    // 3072*1024*2  =  6 MB
    unsigned short* WoutT = (unsigned short*)(ws + 39845888);    // 1024*1024*2  =  2 MB
    unsigned short* qkv   = (unsigned short*)(ws + 41943040);    // 16384*3072*2 = 96 MB
    float* rnq            = (float*)(ws + 142606336);            // 16384*4
    float* kv             = (float*)(ws + 142671872);            // 4096*4

    // 1) casts / weight transposes
    conv_f32_bf16<<<16384, 256, 0, stream>>>(x, x_bf, 16777216);
    transpose_to_bf16<<<dim3(96, 32), 256, 0, stream>>>(Wqkv, WqkvT, 1024, 3072);
    transpose_to_bf16<<<dim3(32, 32), 256, 0, stream>>>(Wout, WoutT, 1024, 1024);

    // 2) qkv = x @ Wqkv + bqkv   (M=16384, N=3072, K=1024) -> bf16
    gemm_bf16<true><<<dim3(128, 24), 256, 0, stream>>>(x_bf, 1024, WqkvT, 1024, bqkv,
                                                       (void*)qkv, 3072, 1024);

    // 3) norms + global kv pool
    hipMemsetAsync(kv, 0, 4096 * sizeof(float), stream);
    norm_kv<<<16384 / NK_ROWS, 256, 0, stream>>>(qkv, rnq, kv, 4096);

    // 4) out = q_hat * kv -> qkv v-region (bf16)
    scale_q<<<16384, 256, 0, stream>>>(qkv, rnq, kv, 4096);

    // 5) y = out @ Wout + bout   (M=16384, N=1024, K=1024) -> fp32 d_out
    gemm_bf16<false><<<dim3(128, 8), 256, 0, stream>>>(qkv + 2048, 3072, WoutT, 1024, bout,
                                                       (void*)out, 1024, 1024);
}

// Round 2
// 378.819 us; speedup vs baseline: 1.1191x; 1.1191x over previous
//
#include <hip/hip_runtime.h>

// ---------- types / helpers ----------
typedef __attribute__((ext_vector_type(8))) short short8;   // 8 bf16 = 4 VGPRs
typedef __attribute__((ext_vector_type(4))) float f32x4;

__device__ __forceinline__ float bf2f(unsigned short u) {
    union { unsigned int i; float f; } x; x.i = ((unsigned int)u) << 16; return x.f;
}
__device__ __forceinline__ unsigned short f2bf(float f) {
    union { float f; unsigned int i; } x; x.f = f;
    unsigned int r = x.i + 0x7fffu + ((x.i >> 16) & 1u);   // RTNE
    return (unsigned short)(r >> 16);
}
__device__ __forceinline__ void async_copy16(const void* g, void* l) {
    __builtin_amdgcn_global_load_lds(
        (const __attribute__((address_space(1))) void*)g,
        (__attribute__((address_space(3))) void*)l,
        16, 0, 0);
}

// ---------- fp32 -> bf16 convert (x) ----------
__global__ __launch_bounds__(256) void conv_f32_bf16(const float* __restrict__ in,
                                                     unsigned short* __restrict__ out, int n) {
    int i = (blockIdx.x * 256 + threadIdx.x) * 4;
    if (i < n) {
        float4 v = *(const float4*)&in[i];
        ushort4 o;
        o.x = f2bf(v.x); o.y = f2bf(v.y); o.z = f2bf(v.z); o.w = f2bf(v.w);
        *(ushort4*)&out[i] = o;
    }
}

// ---------- transpose + convert: in (R x C fp32) -> out (C x R bf16) ----------
__global__ __launch_bounds__(256) void transpose_to_bf16(const float* __restrict__ in,
                                                         unsigned short* __restrict__ out,
                                                         int R, int C) {
    __shared__ float tile[32][33];
    int bx = blockIdx.x * 32;                      // C index
    int by = blockIdx.y * 32;                      // R index
    int tx = threadIdx.x & 31, ty = threadIdx.x >> 5;
    #pragma unroll
    for (int r = ty; r < 32; r += 8)
        tile[r][tx] = in[(size_t)(by + r) * C + bx + tx];
    __syncthreads();
    #pragma unroll
    for (int r = ty; r < 32; r += 8)
        out[(size_t)(bx + r) * R + by + tx] = f2bf(tile[tx][r]);
}

// ---------- bf16 GEMM: C[M,N] = A[M,K] * Bt[N,K]^T + bias ----------
// BM=BN=128, BK=64, 256 threads (4 waves 2x2), wave = 64x64 via 4x4 MFMA 16x16x32.
// LDS chunks XOR-swizzled (cc ^= row&7) -> conflict-free ds_read_b128 fragments.
template<bool OUT_BF16>
__global__ __launch_bounds__(256) void gemm_bf16(const unsigned short* __restrict__ A, int lda,
                                                 const unsigned short* __restrict__ Bt, int ldb,
                                                 const float* __restrict__ bias,
                                                 void* __restrict__ C, int ldc, int K) {
    // K-loop: As = smem[0..8192), Bs = smem[8192..16384)  (each 128 rows x 64 shorts)
    // epilogue (bf16): whole smem reused as tile[128][136]  (17408 shorts = 34816 B)
    __shared__ short smem[17408];
    short* As = smem;
    short* Bs = smem + 8192;

    const int tid    = threadIdx.x;
    const int lane   = tid & 63;
    const int wid    = tid >> 6;
    const int wave_m = wid >> 1, wave_n = wid & 1;
    const int quad   = lane >> 4;
    const int l16    = lane & 15;
    const int m0     = blockIdx.x * 128;
    const int n0     = blockIdx.y * 128;

    f32x4 acc[4][4] = {};

    for (int k0 = 0; k0 < K; k0 += 64) {
        __syncthreads();   // previous iter's LDS reads done
        #pragma unroll
        for (int j = 0; j < 4; j++) {
            const int L = j * 256 + tid;
            const int r = L >> 3;
            const int c = ((L & 7) ^ (r & 7)) * 8;     // swizzled source chunk
            async_copy16(A + (size_t)(m0 + r) * lda + k0 + c, &As[L * 8]);
        }
        #pragma unroll
        for (int j = 0; j < 4; j++) {
            const int L = j * 256 + tid;
            const int r = L >> 3;
            const int c = ((L & 7) ^ (r & 7)) * 8;
            async_copy16(Bt + (size_t)(n0 + r) * ldb + k0 + c, &Bs[L * 8]);
        }
        __syncthreads();   // drain global_load_lds

        #pragma unroll
        for (int kk = 0; kk < 2; kk++) {
            short8 af[4], bfr[4];
            #pragma unroll
            for (int i = 0; i < 4; i++) {
                const int row = wave_m * 64 + i * 16 + l16;
                const int cc  = (quad + kk * 4) ^ (row & 7);
                af[i] = *(const short8*)&As[row * 64 + cc * 8];
            }
            #pragma unroll
            for (int j = 0; j < 4; j++) {
                const int row = wave_n * 64 + j * 16 + l16;
                const int cc  = (quad + kk * 4) ^ (row & 7);
                bfr[j] = *(const short8*)&Bs[row * 64 + cc * 8];
            }
            #pragma unroll
            for (int i = 0; i < 4; i++)
                #pragma unroll
                for (int j = 0; j < 4; j++)
                    acc[i][j] = __builtin_amdgcn_mfma_f32_16x16x32_bf16(af[i], bfr[j], acc[i][j], 0, 0, 0);
        }
    }

    // C/D layout: col = lane&15, row = quad*4 + r   [m89/m91]
    if (OUT_BF16) {
        __syncthreads();                       // all fragment reads done; reuse smem
        unsigned short* tile = (unsigned short*)smem;   // [128][136] padded
        #pragma unroll
        for (int j = 0; j < 4; j++) {
            const int tcol = wave_n * 64 + j * 16 + l16;
            const float bv = bias[n0 + tcol];
            #pragma unroll
            for (int i = 0; i < 4; i++) {
                const int trow = wave_m * 64 + i * 16 + quad * 4;
                #pragma unroll
                for (int r = 0; r < 4; r++)
                    tile[(trow + r) * 136 + tcol] = f2bf(acc[i][j][r] + bv);
            }
        }
        __syncthreads();
        unsigned short* Cp = (unsigned short*)C;
        #pragma unroll
        for (int p = 0; p < 4; p++) {
            const int row = p * 32 + (tid >> 3);
            const int col = (tid & 7) * 16;
            short8 v0 = *(const short8*)&tile[row * 136 + col];
            short8 v1 = *(const short8*)&tile[row * 136 + col + 8];
            *(short8*)&Cp[(size_t)(m0 + row) * ldc + n0 + col]     = v0;
            *(short8*)&Cp[(size_t)(m0 + row) * ldc + n0 + col + 8] = v1;
        }
    } else {
        float* Cp = (float*)C;
        #pragma unroll
        for (int j = 0; j < 4; j++) {
            const int gcol = n0 + wave_n * 64 + j * 16 + l16;
            const float bv = bias[gcol];
            #pragma unroll
            for (int i = 0; i < 4; i++) {
                const int grow = m0 + wave_m * 64 + i * 16 + quad * 4;
                #pragma unroll
                for (int r = 0; r < 4; r++)
                    Cp[(size_t)(grow + r) * ldc + gcol] = acc[i][j][r] + bv;
            }
        }
    }
}

// ---------- per-row q/k norms + kv pool ----------
// One wave per 8 rows: wave-shuffle reductions only (no per-row barriers).
// qkv: [16384][3072] bf16 (q|k|v). grid = 16384/32 blocks, 4 waves/block.
__global__ __launch_bounds__(256) void norm_kv(const unsigned short* __restrict__ qkv,
                                               float* __restrict__ rnq,
                                               float* __restrict__ kv) {
    __shared__ float kvbuf[1024];
    const int tid = threadIdx.x, lane = tid & 63, wv = tid >> 6;
    *(float4*)&kvbuf[tid * 4] = make_float4(0.f, 0.f, 0.f, 0.f);
    __syncthreads();

    const int row0 = blockIdx.x * 32 + wv * 8;
    float a[4][4] = {};

    for (int rr = 0; rr < 8; rr++) {
        const size_t base = (size_t)(row0 + rr) * 3072;
        float q2 = 0.f;
        #pragma unroll
        for (int c = 0; c < 4; c++) {
            ushort4 qu = *(const ushort4*)&qkv[base + c * 256 + lane * 4];
            float x0 = bf2f(qu.x), x1 = bf2f(qu.y), x2 = bf2f(qu.z), x3 = bf2f(qu.w);
            q2 += x0 * x0 + x1 * x1 + x2 * x2 + x3 * x3;
        }
        #pragma unroll
        for (int m = 32; m; m >>= 1) q2 += __shfl_xor(q2, m, 64);
        if (lane == 0) rnq[row0 + rr] = rsqrtf(q2);

        float k2 = 0.f;
        float kf[4][4];
        #pragma unroll
        for (int c = 0; c < 4; c++) {
            ushort4 ku = *(const ushort4*)&qkv[base + 1024 + c * 256 + lane * 4];
            kf[c][0] = bf2f(ku.x); kf[c][1] = bf2f(ku.y);
            kf[c][2] = bf2f(ku.z); kf[c][3] = bf2f(ku.w);
            k2 += kf[c][0]*kf[c][0] + kf[c][1]*kf[c][1] + kf[c][2]*kf[c][2] + kf[c][3]*kf[c][3];
        }
        #pragma unroll
        for (int m = 32; m; m >>= 1) k2 += __shfl_xor(k2, m, 64);
        const float rk = rsqrtf(k2);

        #pragma unroll
        for (int c = 0; c < 4; c++) {
            ushort4 vu = *(const ushort4*)&qkv[base + 2048 + c * 256 + lane * 4];
            a[c][0] += kf[c][0] * rk * bf2f(vu.x);
            a[c][1] += kf[c][1] * rk * bf2f(vu.y);
            a[c][2] += kf[c][2] * rk * bf2f(vu.z);
            a[c][3] += kf[c][3] * rk * bf2f(vu.w);
        }
    }
    #pragma unroll
    for (int c = 0; c < 4; c++)
        #pragma unroll
        for (int i = 0; i < 4; i++)
            atomicAdd(&kvbuf[c * 256 + lane * 4 + i], a[c][i]);
    __syncthreads();
    const int b = blockIdx.x >> 7;     // 128 blocks per batch (4096 rows / 32)
    #pragma unroll
    for (int i = 0; i < 4; i++)
        atomicAdd(&kv[b * 1024 + tid * 4 + i], kvbuf[tid * 4 + i]);
}

// ---------- out = q_hat * kv  (written into qkv's dead v-region, bf16) ----------
__global__ __launch_bounds__(256) void scale_q(unsigned short* __restrict__ qkv,
                                               const float* __restrict__ rnq,
                                               const float* __restrict__ kv, int T) {
    const int t = blockIdx.x;
    const int b = t / T;
    const int d = threadIdx.x * 4;
    const float rq = rnq[t];
    const size_t base = (size_t)t * 3072;
    ushort4 qu = *(const ushort4*)&qkv[base + d];
    float4 kvv = *(const float4*)&kv[b * 1024 + d];
    ushort4 o;
    o.x = f2bf(bf2f(qu.x) * rq * kvv.x);
    o.y = f2bf(bf2f(qu.y) * rq * kvv.y);
    o.z = f2bf(bf2f(qu.z) * rq * kvv.z);
    o.w = f2bf(bf2f(qu.w) * rq * kvv.w);
    *(ushort4*)&qkv[base + 2048 + d] = o;
}

extern "C" void kernel_launch(void* const* d_in, const int* in_sizes, int n_in,
                              void* d_out, int out_size, void* d_ws, size_t ws_size,
                              hipStream_t stream) {
    const float* x    = (const float*)d_in[0];   // (4,4096,1024)
    const float* Wqkv = (const float*)d_in[1];   // (1024,3072)
    const float* bqkv = (const float*)d_in[2];   // (3072)
    const float* Wout = (const float*)d_in[3];   // (1024,1024)
    const float* bout = (const float*)d_in[4];   // (1024)
    float* out = (float*)d_out;                  // (4,4096,1024) fp32

    // workspace layout (~136 MB)
    char* ws = (char*)d_ws;
    unsigned short* x_bf  = (unsigned short*)(ws + 0);           // 32 MB
    unsigned short* WqkvT = (unsigned short*)(ws + 33554432);    // 6 MB
    unsigned short* WoutT = (unsigned short*)(ws + 39845888);    // 2 MB
    unsigned short* qkv   = (unsigned short*)(ws + 41943040);    // 96 MB
    float* rnq            = (float*)(ws + 142606336);            // 64 KB
    float* kv             = (float*)(ws + 142671872);            // 16 KB

    conv_f32_bf16<<<16384, 256, 0, stream>>>(x, x_bf, 16777216);
    transpose_to_bf16<<<dim3(96, 32), 256, 0, stream>>>(Wqkv, WqkvT, 1024, 3072);
    transpose_to_bf16<<<dim3(32, 32), 256, 0, stream>>>(Wout, WoutT, 1024, 1024);

    // qkv = x @ Wqkv + bqkv   (M=16384, N=3072, K=1024) -> bf16
    gemm_bf16<true><<<dim3(128, 24), 256, 0, stream>>>(x_bf, 1024, WqkvT, 1024, bqkv,
                                                       (void*)qkv, 3072, 1024);

    hipMemsetAsync(kv, 0, 4096 * sizeof(float), stream);
    norm_kv<<<512, 256, 0, stream>>>(qkv, rnq, kv);

    scale_q<<<16384, 256, 0, stream>>>(qkv, rnq, kv, 4096);

    // y = out @ Wout + bout   (M=16384, N=1024, K=1024) -> fp32 d_out
    gemm_bf16<false><<<dim3(128, 8), 256, 0, stream>>>(qkv + 2048, 3072, WoutT, 1024, bout,
                                                       (void*)out, 1024, 1024);
}